// Round 10
// baseline (184.234 us; speedup 1.0000x reference)
//
#include <hip/hip_runtime.h>

// NCC loss, win=9, (1,1,160,192,224) fp32 -> scalar. Fully fused, round 10.
// KEY CHANGE: LDS 44.8 -> 27.5 KB (SW single-buffered) to get 2 blocks/CU
// co-resident. Counter forensics R5-R9: dur invariant at ~70us with VALUBusy
// 30% == exactly 1 resident block (625 issue cyc / 2100 cyc per slice);
// R2 (23.5 KB) showed VALUBusy 50% == 2 resident. Hypothesis: co-residency
// LDS budget ~64 KB, so 45 KB => 1 block and zero stall-hiding.
// Re-phased pipeline makes SW single-buffer safe:
//   phase1: W-group(192t): W-sums for slice i+1 from prefetched regs -> ws REGS
//        || H-group(160t): H 9-tap column-slide over SW(i) -> SH(i)
//   barA (lds-only)
//   phase2: W-group: ws regs -> SW(i+1) (b128, stride 36); issue z+2 prefetch
//        || F (all 512t): read SH(i) [ch-interleaved], O(1) D-ring, cc
//   barB (lds-only)
// Hazards: W-write(i+1) vs H-read(i): barA. H-write(i+1) vs F-read(i): barB.
// DCH=19 -> ITERS=27=3x9 (phase-static ring), 756 blocks.

#define DD 160
#define HH 192
#define WW 224
#define W4 56                 // WW/4
#define SLICE (HH * WW)
#define S4 (SLICE / 4)
#define NVOX (DD * SLICE)
#define TW 32
#define TH 16
#define DCH 19                // grid.z = 9 -> 756 blocks
#define ITERS (DCH + 8)       // 27 = 3 * 9 exactly
#define NTHR 512
#define SW_RS 36              // b128-aligned rows; 0-conflict measured (R5/R7)
#define SW_CS (24 * SW_RS)    // 864
#define EPS 1e-5f
#define INV_WSUM (1.0f / 729.0f)

// LDS-only barrier: s_waitcnt lgkmcnt(0) (vmcnt unconstrained) + s_barrier.
// Keeps the W-group's global register-prefetch in flight across barriers.
__device__ __forceinline__ void bar_lds_only() {
    __asm__ volatile("" ::: "memory");
    __builtin_amdgcn_s_waitcnt(0xC07F);
    __builtin_amdgcn_s_barrier();
    __asm__ volatile("" ::: "memory");
}

__global__ __launch_bounds__(NTHR, 4) void ncc_fused(const float* __restrict__ I,
                                                     const float* __restrict__ J,
                                                     float* __restrict__ out) {
    __shared__ float SW[5 * SW_CS];       // 17.28 KB, single-buffered
    __shared__ float SH[TH * TW * 5];     // 10.24 KB, [row][col][ch]
    __shared__ float wred[NTHR / 64];

    const int tid = threadIdx.x;
    const int tx = tid & 31, ty = tid >> 5;
    const int wlo = blockIdx.x * TW;
    const int hlo = blockIdx.y * TH;
    const int dlo = blockIdx.z * DCH;

    // W-group (tid < 192): 24 rows x 8 f4-col groups
    const int wr = tid >> 3, wc = tid & 7;
    const int gh = hlo - 4 + wr;
    const bool hok = (gh >= 0) && (gh < HH);
    const int gf0 = (wlo >> 2) - 1 + wc;

    // H-group (tid in [192,352)): 5 channels x 32 cols
    const int ht = tid - 192;
    const int hcol = ht & 31, hch = ht >> 5;

    const float4* Iv = (const float4*)I;
    const float4* Jv = (const float4*)J;

    float pfa[12], pfb[12];   // raw I/J prefetch for the next staged slice
    float ws[20];             // 5ch x f4 W-sums, carried phase1 -> phase2

    auto w_load = [&](int z) {   // fill pfa/pfb for slice z (zeros if OOB)
        const bool zok = (z >= 0) && (z < DD) && hok;
        const int rowb = z * S4 + gh * W4;
        #pragma unroll
        for (int k = 0; k < 3; ++k) {
            const int f = gf0 + k;
            float4 a = make_float4(0.f, 0.f, 0.f, 0.f);
            float4 b = make_float4(0.f, 0.f, 0.f, 0.f);
            if (zok && f >= 0 && f < W4) { a = Iv[rowb + f]; b = Jv[rowb + f]; }
            pfa[4*k] = a.x; pfa[4*k+1] = a.y; pfa[4*k+2] = a.z; pfa[4*k+3] = a.w;
            pfb[4*k] = b.x; pfb[4*k+1] = b.y; pfb[4*k+2] = b.z; pfb[4*k+3] = b.w;
        }
    };

    auto w_comp = [&]() {   // sliding 9-tap W-sums from pfa/pfb -> ws regs
        #pragma unroll
        for (int ch = 0; ch < 5; ++ch) {
            float v[12];
            #pragma unroll
            for (int k = 0; k < 12; ++k)
                v[k] = (ch == 0) ? pfa[k]
                     : (ch == 1) ? pfb[k]
                     : (ch == 2) ? pfa[k] * pfa[k]
                     : (ch == 3) ? pfb[k] * pfb[k]
                     :             pfa[k] * pfb[k];
            float s = v[0];
            #pragma unroll
            for (int k = 1; k < 9; ++k) s += v[k];
            ws[4*ch] = s;
            s += v[9]  - v[0]; ws[4*ch+1] = s;
            s += v[10] - v[1]; ws[4*ch+2] = s;
            s += v[11] - v[2]; ws[4*ch+3] = s;
        }
    };

    auto w_store = [&]() {   // ws regs -> SW (b128, 16B-aligned)
        float* wp = SW + wr * SW_RS + 4 * wc;
        #pragma unroll
        for (int ch = 0; ch < 5; ++ch)
            *(float4*)(wp + ch * SW_CS) =
                make_float4(ws[4*ch], ws[4*ch+1], ws[4*ch+2], ws[4*ch+3]);
    };

    float q0[9], q1[9], q2[9], q3[9], q4[9];
    #pragma unroll
    for (int k = 0; k < 9; ++k) { q0[k]=0.f; q1[k]=0.f; q2[k]=0.f; q3[k]=0.f; q4[k]=0.f; }
    float r0=0.f, r1=0.f, r2=0.f, r3=0.f, r4=0.f;
    float acc = 0.f;

    // prologue: slice z0 = dlo-4 -> SW; prefetch z1 = dlo-3 into pf regs
    if (tid < 192) {
        w_load(dlo - 4);
        if (dlo >= 4) { w_comp(); w_store(); }   // dlo=0 -> z0<0, SW stale, masked
        w_load(dlo - 3);
    }
    bar_lds_only();

    #pragma unroll 1
    for (int g = 0; g < 3; ++g) {
        #pragma unroll
        for (int ph = 0; ph < 9; ++ph) {
            const int i = 9 * g + ph;
            const int z = dlo - 4 + i;
            const bool val = (z >= 0) && (z < DD);     // block-uniform
            const bool nxt = (i < ITERS - 1) && (z + 1 >= 0) && (z + 1 < DD);

            // ---- phase1: W(i+1) -> regs  ||  H(i): SW -> SH ----
            if (tid < 192) {
                if (nxt) w_comp();                     // consume prefetch
            } else if (ht < 160 && val) {
                const float* p = SW + hch * SW_CS + hcol;
                float v[24];
                #pragma unroll
                for (int r = 0; r < 24; r += 2) {      // pairs -> ds_read2_b32
                    const float* pr = p + r * SW_RS;
                    v[r]     = pr[0];
                    v[r + 1] = pr[SW_RS];
                }
                float s = v[0];
                #pragma unroll
                for (int r = 1; r < 9; ++r) s += v[r];
                float* o = SH + hcol * 5 + hch;        // [row][col][ch]
                float prev = s;
                o[0] = s;
                #pragma unroll
                for (int r = 1; r < 16; ++r) {
                    prev += v[r + 8] - v[r - 1];
                    o[r * (TW * 5)] = prev;
                }
            }
            bar_lds_only();   // barA: SH(i) -> F; SW safe for W write

            // ---- phase2: W writes SW(i+1) + prefetch z+2  ||  F(i) ----
            if (tid < 192) {
                if (nxt) w_store();
                if (i < ITERS - 2) w_load(z + 2);      // refill prefetch
            }
            float w0=0.f, w1=0.f, w2=0.f, w3=0.f, w4=0.f;
            if (val) {
                const float* p = SH + (ty * TW + tx) * 5;
                w0 = p[0]; w1 = p[1]; w2 = p[2]; w3 = p[3]; w4 = p[4];
            }
            r0 += w0 - q0[ph]; q0[ph] = w0;
            r1 += w1 - q1[ph]; q1[ph] = w1;
            r2 += w2 - q2[ph]; q2[ph] = w2;
            r3 += w3 - q3[ph]; q3[ph] = w3;
            r4 += w4 - q4[ph]; q4[ph] = w4;

            if (i >= 8 && (dlo + i - 8) < DD) {        // last chunk overhangs
                float cross = r4 - r0 * r1 * INV_WSUM;
                float iv    = r2 - r0 * r0 * INV_WSUM;
                float jv    = r3 - r1 * r1 * INV_WSUM;
                acc += cross * cross * __builtin_amdgcn_rcpf(iv * jv + EPS);
            }
            bar_lds_only();   // barB: F done with SH; H(i+1) may write
        }
    }

    // ---- block reduction -> one atomic ----
    #pragma unroll
    for (int off = 32; off > 0; off >>= 1) acc += __shfl_down(acc, off, 64);
    if ((tid & 63) == 0) wred[tid >> 6] = acc;
    __syncthreads();
    if (tid == 0) {
        float t = 0.f;
        #pragma unroll
        for (int k = 0; k < NTHR / 64; ++k) t += wred[k];
        atomicAdd(out, t * (-1.0f / (float)NVOX));
    }
}

extern "C" void kernel_launch(void* const* d_in, const int* in_sizes, int n_in,
                              void* d_out, int out_size, void* d_ws, size_t ws_size,
                              hipStream_t stream) {
    const float* I = (const float*)d_in[0];
    const float* J = (const float*)d_in[1];
    float* out = (float*)d_out;

    hipMemsetAsync(d_out, 0, sizeof(float), stream);  // harness re-poisons d_out

    dim3 blk(NTHR, 1, 1);
    dim3 grd(WW / TW, HH / TH, (DD + DCH - 1) / DCH); // 7 x 12 x 9 = 756 blocks
    ncc_fused<<<grd, blk, 0, stream>>>(I, J, out);
}

// Round 11
// 167.165 us; speedup vs baseline: 1.1021x; 1.1021x over previous
//
#include <hip/hip_runtime.h>

// NCC loss, win=9, (1,1,160,192,224) fp32 -> scalar. Fully fused, round 11.
// == R9 + DEPTH-2 register prefetch + __launch_bounds__(512,2).
// Why: R5-R9 sat at ~70us with ~2100 cyc/block-slice vs ~600 issued. The
// exposed term is cold-HBM latency (~900-1200 cyc): R8/R9 issued the next
// slice's loads only ONE barrier before use. Depth-2 pipeline (sets A,B;
// consume A, copy A<-B, load S(i+3)->B) gives the loads ~2 slice-cycles in
// flight. R9's lgkmcnt-only barrier is what lets them survive the barriers.
// (512,2) raises the compiler VGPR cap to ~128: live set ~115 regs, no spill
// (R6/R10 both died of launch-bounds-induced scratch spill; gate = WRITE_SIZE).
//   phase1: waves 0-2 (192t): w_compute consumes A -> SW[(i+1)&1] (b128,
//           stride 36, 0-conflict); A <- B (movs); issue loads S(i+3) -> B.
//        || waves 3-5 (160t): H(i) paired col-reads over SW[i&1] -> SH.
//   barA (lgkm-only);  F(i): 512t read SH, O(1) D-ring, cc;  barB (lgkm-only).
// DCH=19 -> ITERS=27=3x9 (phase-static ring), 756 blocks.

#define DD 160
#define HH 192
#define WW 224
#define W4 56                 // WW/4
#define SLICE (HH * WW)
#define S4 (SLICE / 4)
#define NVOX (DD * SLICE)
#define TW 32
#define TH 16
#define DCH 19                // grid.z = 9 -> 756 blocks
#define ITERS (DCH + 8)       // 27 = 3 * 9 exactly
#define NTHR 512
#define SW_RS 36              // b128-aligned rows; 0-conflict measured (R5/R7)
#define SW_CS (24 * SW_RS)    // 864
#define EPS 1e-5f
#define INV_WSUM (1.0f / 729.0f)

// LDS-only barrier: s_waitcnt lgkmcnt(0) (vmcnt unconstrained) + s_barrier.
// Keeps the W-group's global register-prefetch in flight across barriers.
__device__ __forceinline__ void bar_lds_only() {
    __asm__ volatile("" ::: "memory");
    __builtin_amdgcn_s_waitcnt(0xC07F);
    __builtin_amdgcn_s_barrier();
    __asm__ volatile("" ::: "memory");
}

__global__ __launch_bounds__(NTHR, 2) void ncc_fused(const float* __restrict__ I,
                                                     const float* __restrict__ J,
                                                     float* __restrict__ out) {
    __shared__ float SW0[5 * SW_CS], SW1[5 * SW_CS];   // 17.28 KB each
    __shared__ float SH[TH * TW * 5];                  // 10.24 KB, [row][col][ch]
    __shared__ float wred[NTHR / 64];

    const int tid = threadIdx.x;
    const int tx = tid & 31, ty = tid >> 5;
    const int wlo = blockIdx.x * TW;
    const int hlo = blockIdx.y * TH;
    const int dlo = blockIdx.z * DCH;

    // W-group (tid < 192): 24 rows x 8 f4-col groups
    const int wr = tid >> 3, wc = tid & 7;
    const int gh = hlo - 4 + wr;
    const bool hok = (gh >= 0) && (gh < HH);
    const int gf0 = (wlo >> 2) - 1 + wc;

    // H-group (tid in [192,352)): 5 channels x 32 cols
    const int ht = tid - 192;
    const int hcol = ht & 31, hch = ht >> 5;

    const float4* Iv = (const float4*)I;
    const float4* Jv = (const float4*)J;

    // depth-2 prefetch: set A (consumed next) and set B (landing zone)
    float pfa[12], pfb[12];   // A: raw I/J for slice S(i+1)
    float pca[12], pcb[12];   // B: raw I/J for slice S(i+2)/(i+3) in flight

    auto load_to = [&](float* da, float* db, int z) {  // zeros if OOB
        const bool zok = (z >= 0) && (z < DD) && hok;
        const int rowb = z * S4 + gh * W4;
        #pragma unroll
        for (int k = 0; k < 3; ++k) {
            const int f = gf0 + k;
            float4 a = make_float4(0.f, 0.f, 0.f, 0.f);
            float4 b = make_float4(0.f, 0.f, 0.f, 0.f);
            if (zok && f >= 0 && f < W4) { a = Iv[rowb + f]; b = Jv[rowb + f]; }
            da[4*k] = a.x; da[4*k+1] = a.y; da[4*k+2] = a.z; da[4*k+3] = a.w;
            db[4*k] = b.x; db[4*k+1] = b.y; db[4*k+2] = b.z; db[4*k+3] = b.w;
        }
    };

    auto w_compute = [&](float* dst) {   // slide 9-tap W-sums from set A -> dst
        float* wp = dst + wr * SW_RS + 4 * wc;
        #pragma unroll
        for (int ch = 0; ch < 5; ++ch) {
            float v[12];
            #pragma unroll
            for (int k = 0; k < 12; ++k)
                v[k] = (ch == 0) ? pfa[k]
                     : (ch == 1) ? pfb[k]
                     : (ch == 2) ? pfa[k] * pfa[k]
                     : (ch == 3) ? pfb[k] * pfb[k]
                     :             pfa[k] * pfb[k];
            float s = v[0];
            #pragma unroll
            for (int k = 1; k < 9; ++k) s += v[k];
            float4 o;
            o.x = s;
            s += v[9]  - v[0]; o.y = s;
            s += v[10] - v[1]; o.z = s;
            s += v[11] - v[2]; o.w = s;
            *(float4*)(wp + ch * SW_CS) = o;   // b128, 16B-aligned
        }
    };

    float q0[9], q1[9], q2[9], q3[9], q4[9];
    #pragma unroll
    for (int k = 0; k < 9; ++k) { q0[k]=0.f; q1[k]=0.f; q2[k]=0.f; q3[k]=0.f; q4[k]=0.f; }
    float r0=0.f, r1=0.f, r2=0.f, r3=0.f, r4=0.f;
    float acc = 0.f;

    // prologue: S(0)=dlo-4 -> SW0; A=S(1), B=S(2)
    if (tid < 192) {
        load_to(pfa, pfb, dlo - 4);
        if (dlo >= 4) w_compute(SW0);       // slice S(0); masked by val if OOB
        load_to(pfa, pfb, dlo - 3);         // A = S(1)
        load_to(pca, pcb, dlo - 2);         // B = S(2)
    }
    bar_lds_only();

    #pragma unroll 1
    for (int g = 0; g < 3; ++g) {
        #pragma unroll
        for (int ph = 0; ph < 9; ++ph) {
            const int i = 9 * g + ph;
            const int z = dlo - 4 + i;
            const bool val = (z >= 0) && (z < DD);   // block-uniform
            const int par = i & 1;
            float* swR = par ? SW1 : SW0;
            float* swW = par ? SW0 : SW1;

            if (tid < 192) {
                if (i < ITERS - 1) {
                    const int zn = z + 1;                    // slice S(i+1) in A
                    if (zn >= 0 && zn < DD) w_compute(swW);  // consume A
                    #pragma unroll
                    for (int k = 0; k < 12; ++k) {           // A <- B (S(i+2))
                        pfa[k] = pca[k]; pfb[k] = pcb[k];
                    }
                    if (i < ITERS - 3) load_to(pca, pcb, z + 3);  // B = S(i+3)
                }
            } else if (ht < 160 && val) {
                const float* p = swR + hch * SW_CS + hcol;
                float v[24];
                #pragma unroll
                for (int r = 0; r < 24; r += 2) {       // pairs -> ds_read2_b32
                    const float* pr = p + r * SW_RS;
                    v[r]     = pr[0];
                    v[r + 1] = pr[SW_RS];
                }
                float s = v[0];
                #pragma unroll
                for (int r = 1; r < 9; ++r) s += v[r];
                float* o = SH + hcol * 5 + hch;         // [row][col][ch]
                float prev = s;
                o[0] = s;
                #pragma unroll
                for (int r = 1; r < 16; ++r) {
                    prev += v[r + 8] - v[r - 1];
                    o[r * (TW * 5)] = prev;
                }
            }
            bar_lds_only();    // barA: SH(i) visible to F (LDS-only ordering)

            float w0=0.f, w1=0.f, w2=0.f, w3=0.f, w4=0.f;
            if (val) {
                const float* p = SH + (ty * TW + tx) * 5;
                w0 = p[0]; w1 = p[1]; w2 = p[2]; w3 = p[3]; w4 = p[4];
            }
            r0 += w0 - q0[ph]; q0[ph] = w0;
            r1 += w1 - q1[ph]; q1[ph] = w1;
            r2 += w2 - q2[ph]; q2[ph] = w2;
            r3 += w3 - q3[ph]; q3[ph] = w3;
            r4 += w4 - q4[ph]; q4[ph] = w4;

            if (i >= 8 && (dlo + i - 8) < DD) {   // last chunk overhangs to 171
                float cross = r4 - r0 * r1 * INV_WSUM;
                float iv    = r2 - r0 * r0 * INV_WSUM;
                float jv    = r3 - r1 * r1 * INV_WSUM;
                acc += cross * cross * __builtin_amdgcn_rcpf(iv * jv + EPS);
            }
            bar_lds_only();    // barB: F done with SH; H(i+1)/W(i+2) may proceed
        }
    }

    // ---- block reduction -> one atomic ----
    #pragma unroll
    for (int off = 32; off > 0; off >>= 1) acc += __shfl_down(acc, off, 64);
    if ((tid & 63) == 0) wred[tid >> 6] = acc;
    __syncthreads();
    if (tid == 0) {
        float t = 0.f;
        #pragma unroll
        for (int k = 0; k < NTHR / 64; ++k) t += wred[k];
        atomicAdd(out, t * (-1.0f / (float)NVOX));
    }
}

extern "C" void kernel_launch(void* const* d_in, const int* in_sizes, int n_in,
                              void* d_out, int out_size, void* d_ws, size_t ws_size,
                              hipStream_t stream) {
    const float* I = (const float*)d_in[0];
    const float* J = (const float*)d_in[1];
    float* out = (float*)d_out;

    hipMemsetAsync(d_out, 0, sizeof(float), stream);  // harness re-poisons d_out

    dim3 blk(NTHR, 1, 1);
    dim3 grd(WW / TW, HH / TH, (DD + DCH - 1) / DCH); // 7 x 12 x 9 = 756 blocks
    ncc_fused<<<grd, blk, 0, stream>>>(I, J, out);
}

// Round 12
// 151.134 us; speedup vs baseline: 1.2190x; 1.1061x over previous
//
#include <hip/hip_runtime.h>

// NCC loss, win=9, (1,1,160,192,224) fp32 -> scalar. Fully fused, round 12.
// THEORY (12-round synthesis): resident blocks/CU = floor(64KB / LDS), so the
// 45-KB variants ran ONE block/CU -> every barrier/latency cycle exposed ->
// the ~70us plateau. R10 cut LDS to 27.5KB (single-buffered SW) but
// __launch_bounds__(512,4) made the compiler pick 64 VGPR and spill 138MB.
// R12 = R10 phasing + __launch_bounds__(512,2) (R11-measured: 92 VGPR, no
// spill; <=128 still allows 2 blocks = 16 waves/CU).
//   phase1: W-group(192t): W-sums for slice i+1 from prefetched regs -> ws REGS
//        || H-group(160t): H 9-tap column-slide over SW(i) -> SH(i)
//   barA (lgkm-only)
//   phase2: W-group: ws regs -> SW(i+1) (b128, stride 36); issue z+2 prefetch
//        || F (all 512t): read SH(i) [ch-interleaved], O(1) D-ring, cc
//   barB (lgkm-only)
// Hazards: W-write(i+1) vs H-read(i): barA. H-write(i+1) vs F-read(i): barB.
// DCH=19 -> ITERS=27=3x9 (phase-static ring), 756 blocks. LDS 27.6 KB.

#define DD 160
#define HH 192
#define WW 224
#define W4 56                 // WW/4
#define SLICE (HH * WW)
#define S4 (SLICE / 4)
#define NVOX (DD * SLICE)
#define TW 32
#define TH 16
#define DCH 19                // grid.z = 9 -> 756 blocks
#define ITERS (DCH + 8)       // 27 = 3 * 9 exactly
#define NTHR 512
#define SW_RS 36              // b128-aligned rows; 0-conflict measured (R5/R7)
#define SW_CS (24 * SW_RS)    // 864
#define EPS 1e-5f
#define INV_WSUM (1.0f / 729.0f)

// LDS-only barrier: s_waitcnt lgkmcnt(0) (vmcnt unconstrained) + s_barrier.
// Keeps the W-group's global register-prefetch in flight across barriers.
__device__ __forceinline__ void bar_lds_only() {
    __asm__ volatile("" ::: "memory");
    __builtin_amdgcn_s_waitcnt(0xC07F);
    __builtin_amdgcn_s_barrier();
    __asm__ volatile("" ::: "memory");
}

__global__ __launch_bounds__(NTHR, 2) void ncc_fused(const float* __restrict__ I,
                                                     const float* __restrict__ J,
                                                     float* __restrict__ out) {
    __shared__ float SW[5 * SW_CS];       // 17.28 KB, single-buffered
    __shared__ float SH[TH * TW * 5];     // 10.24 KB, [row][col][ch]
    __shared__ float wred[NTHR / 64];

    const int tid = threadIdx.x;
    const int tx = tid & 31, ty = tid >> 5;
    const int wlo = blockIdx.x * TW;
    const int hlo = blockIdx.y * TH;
    const int dlo = blockIdx.z * DCH;

    // W-group (tid < 192): 24 rows x 8 f4-col groups
    const int wr = tid >> 3, wc = tid & 7;
    const int gh = hlo - 4 + wr;
    const bool hok = (gh >= 0) && (gh < HH);
    const int gf0 = (wlo >> 2) - 1 + wc;

    // H-group (tid in [192,352)): 5 channels x 32 cols
    const int ht = tid - 192;
    const int hcol = ht & 31, hch = ht >> 5;

    const float4* Iv = (const float4*)I;
    const float4* Jv = (const float4*)J;

    float pfa[12], pfb[12];   // raw I/J prefetch for the next staged slice
    float ws[20];             // 5ch x f4 W-sums, carried phase1 -> phase2

    auto w_load = [&](int z) {   // fill pfa/pfb for slice z (zeros if OOB)
        const bool zok = (z >= 0) && (z < DD) && hok;
        const int rowb = z * S4 + gh * W4;
        #pragma unroll
        for (int k = 0; k < 3; ++k) {
            const int f = gf0 + k;
            float4 a = make_float4(0.f, 0.f, 0.f, 0.f);
            float4 b = make_float4(0.f, 0.f, 0.f, 0.f);
            if (zok && f >= 0 && f < W4) { a = Iv[rowb + f]; b = Jv[rowb + f]; }
            pfa[4*k] = a.x; pfa[4*k+1] = a.y; pfa[4*k+2] = a.z; pfa[4*k+3] = a.w;
            pfb[4*k] = b.x; pfb[4*k+1] = b.y; pfb[4*k+2] = b.z; pfb[4*k+3] = b.w;
        }
    };

    auto w_comp = [&]() {   // sliding 9-tap W-sums from pfa/pfb -> ws regs
        #pragma unroll
        for (int ch = 0; ch < 5; ++ch) {
            float v[12];
            #pragma unroll
            for (int k = 0; k < 12; ++k)
                v[k] = (ch == 0) ? pfa[k]
                     : (ch == 1) ? pfb[k]
                     : (ch == 2) ? pfa[k] * pfa[k]
                     : (ch == 3) ? pfb[k] * pfb[k]
                     :             pfa[k] * pfb[k];
            float s = v[0];
            #pragma unroll
            for (int k = 1; k < 9; ++k) s += v[k];
            ws[4*ch] = s;
            s += v[9]  - v[0]; ws[4*ch+1] = s;
            s += v[10] - v[1]; ws[4*ch+2] = s;
            s += v[11] - v[2]; ws[4*ch+3] = s;
        }
    };

    auto w_store = [&]() {   // ws regs -> SW (b128, 16B-aligned)
        float* wp = SW + wr * SW_RS + 4 * wc;
        #pragma unroll
        for (int ch = 0; ch < 5; ++ch)
            *(float4*)(wp + ch * SW_CS) =
                make_float4(ws[4*ch], ws[4*ch+1], ws[4*ch+2], ws[4*ch+3]);
    };

    float q0[9], q1[9], q2[9], q3[9], q4[9];
    #pragma unroll
    for (int k = 0; k < 9; ++k) { q0[k]=0.f; q1[k]=0.f; q2[k]=0.f; q3[k]=0.f; q4[k]=0.f; }
    float r0=0.f, r1=0.f, r2=0.f, r3=0.f, r4=0.f;
    float acc = 0.f;

    // prologue: slice z0 = dlo-4 -> SW; prefetch z1 = dlo-3 into pf regs
    if (tid < 192) {
        w_load(dlo - 4);
        if (dlo >= 4) { w_comp(); w_store(); }   // dlo=0 -> z0<0, SW stale, masked
        w_load(dlo - 3);
    }
    bar_lds_only();

    #pragma unroll 1
    for (int g = 0; g < 3; ++g) {
        #pragma unroll
        for (int ph = 0; ph < 9; ++ph) {
            const int i = 9 * g + ph;
            const int z = dlo - 4 + i;
            const bool val = (z >= 0) && (z < DD);     // block-uniform
            const bool nxt = (i < ITERS - 1) && (z + 1 >= 0) && (z + 1 < DD);

            // ---- phase1: W(i+1) -> regs  ||  H(i): SW -> SH ----
            if (tid < 192) {
                if (nxt) w_comp();                     // consume prefetch
            } else if (ht < 160 && val) {
                const float* p = SW + hch * SW_CS + hcol;
                float v[24];
                #pragma unroll
                for (int r = 0; r < 24; r += 2) {      // pairs -> ds_read2_b32
                    const float* pr = p + r * SW_RS;
                    v[r]     = pr[0];
                    v[r + 1] = pr[SW_RS];
                }
                float s = v[0];
                #pragma unroll
                for (int r = 1; r < 9; ++r) s += v[r];
                float* o = SH + hcol * 5 + hch;        // [row][col][ch]
                float prev = s;
                o[0] = s;
                #pragma unroll
                for (int r = 1; r < 16; ++r) {
                    prev += v[r + 8] - v[r - 1];
                    o[r * (TW * 5)] = prev;
                }
            }
            bar_lds_only();   // barA: SH(i) -> F; SW safe for W write

            // ---- phase2: W writes SW(i+1) + prefetch z+2  ||  F(i) ----
            if (tid < 192) {
                if (nxt) w_store();
                if (i < ITERS - 2) w_load(z + 2);      // refill prefetch
            }
            float w0=0.f, w1=0.f, w2=0.f, w3=0.f, w4=0.f;
            if (val) {
                const float* p = SH + (ty * TW + tx) * 5;
                w0 = p[0]; w1 = p[1]; w2 = p[2]; w3 = p[3]; w4 = p[4];
            }
            r0 += w0 - q0[ph]; q0[ph] = w0;
            r1 += w1 - q1[ph]; q1[ph] = w1;
            r2 += w2 - q2[ph]; q2[ph] = w2;
            r3 += w3 - q3[ph]; q3[ph] = w3;
            r4 += w4 - q4[ph]; q4[ph] = w4;

            if (i >= 8 && (dlo + i - 8) < DD) {        // last chunk overhangs
                float cross = r4 - r0 * r1 * INV_WSUM;
                float iv    = r2 - r0 * r0 * INV_WSUM;
                float jv    = r3 - r1 * r1 * INV_WSUM;
                acc += cross * cross * __builtin_amdgcn_rcpf(iv * jv + EPS);
            }
            bar_lds_only();   // barB: F done with SH; H(i+1) may write
        }
    }

    // ---- block reduction -> one atomic ----
    #pragma unroll
    for (int off = 32; off > 0; off >>= 1) acc += __shfl_down(acc, off, 64);
    if ((tid & 63) == 0) wred[tid >> 6] = acc;
    __syncthreads();
    if (tid == 0) {
        float t = 0.f;
        #pragma unroll
        for (int k = 0; k < NTHR / 64; ++k) t += wred[k];
        atomicAdd(out, t * (-1.0f / (float)NVOX));
    }
}

extern "C" void kernel_launch(void* const* d_in, const int* in_sizes, int n_in,
                              void* d_out, int out_size, void* d_ws, size_t ws_size,
                              hipStream_t stream) {
    const float* I = (const float*)d_in[0];
    const float* J = (const float*)d_in[1];
    float* out = (float*)d_out;

    hipMemsetAsync(d_out, 0, sizeof(float), stream);  // harness re-poisons d_out

    dim3 blk(NTHR, 1, 1);
    dim3 grd(WW / TW, HH / TH, (DD + DCH - 1) / DCH); // 7 x 12 x 9 = 756 blocks
    ncc_fused<<<grd, blk, 0, stream>>>(I, J, out);
}